// Round 3
// baseline (270.366 us; speedup 1.0000x reference)
//
#include <hip/hip_runtime.h>
#include <hip/hip_bf16.h>
#include <math.h>

#define NI 1024        // NUM_INPUTS
#define NH 1024        // NUM_HIDDEN
#define H4 4096        // 4*NUM_HIDDEN
#define FGB (-1.0f)
#define LN_EPS 1e-5f

typedef unsigned short u16;
typedef __attribute__((ext_vector_type(8))) short short8;      // 8 bf16 (MFMA frag)
typedef __attribute__((ext_vector_type(8))) unsigned short ushort8v;
typedef __attribute__((ext_vector_type(4))) float f32x4;

__device__ __forceinline__ float bf2f(u16 u) {
    union { unsigned int i; float f; } v; v.i = ((unsigned int)u) << 16; return v.f;
}
__device__ __forceinline__ u16 f2bf(float f) {
    __hip_bfloat16 h = __float2bfloat16(f);   // RNE
    return __builtin_bit_cast(u16, h);
}
__device__ __forceinline__ ushort8v cvt8(float4 lo, float4 hi) {
    ushort8v r;
    r[0] = f2bf(lo.x); r[1] = f2bf(lo.y); r[2] = f2bf(lo.z); r[3] = f2bf(lo.w);
    r[4] = f2bf(hi.x); r[5] = f2bf(hi.y); r[6] = f2bf(hi.z); r[7] = f2bf(hi.w);
    return r;
}
__device__ __forceinline__ float fast_sigmoid(float x) {
    return 1.0f / (1.0f + __expf(-x));
}
__device__ __forceinline__ float fast_tanh(float x) {
    return 1.0f - 2.0f / (__expf(2.0f * x) + 1.0f);
}
__device__ __forceinline__ void ld8(const float* p, float* d) {
    float4 a = *(const float4*)p;
    float4 b = *(const float4*)(p + 4);
    d[0] = a.x; d[1] = a.y; d[2] = a.z; d[3] = a.w;
    d[4] = b.x; d[5] = b.y; d[6] = b.z; d[7] = b.w;
}
__device__ __forceinline__ void st8(float* p, const float* s) {
    *(float4*)p       = make_float4(s[0], s[1], s[2], s[3]);
    *(float4*)(p + 4) = make_float4(s[4], s[5], s[6], s[7]);
}
__device__ __forceinline__ void gload_lds16(const u16* g, u16* l) {
    __builtin_amdgcn_global_load_lds(
        (__attribute__((address_space(1))) void*)(g),
        (__attribute__((address_space(3))) void*)(l), 16, 0, 0);
}

// ---------------------------------------------------------------------------
// fp32 -> bf16 cast, 8 elems/thread, 16B stores
// ---------------------------------------------------------------------------
__global__ __launch_bounds__(256) void cast4(
    const float* __restrict__ a, const float* __restrict__ b,
    const float* __restrict__ c, const float* __restrict__ d,
    u16* __restrict__ oa, u16* __restrict__ ob,
    u16* __restrict__ oc, u16* __restrict__ od)
{
    const int i = (blockIdx.x * 256 + threadIdx.x) * 8;
    *(ushort8v*)(oa + i) = cvt8(*(const float4*)(a + i), *(const float4*)(a + i + 4));
    *(ushort8v*)(ob + i) = cvt8(*(const float4*)(b + i), *(const float4*)(b + i + 4));
    *(ushort8v*)(oc + i) = cvt8(*(const float4*)(c + i), *(const float4*)(c + i + 4));
    *(ushort8v*)(od + i) = cvt8(*(const float4*)(d + i), *(const float4*)(d + i + 4));
}

// ---------------------------------------------------------------------------
// C[M,N](bf16) = A[M,K](bf16) @ W[N,K](bf16)^T + bias[N](fp32)
// m97 structure + coalesced epilogue via wave-private LDS transpose.
// ---------------------------------------------------------------------------
__global__ __launch_bounds__(256) void gemm_bt_bf16(
    const u16* __restrict__ A0, const u16* __restrict__ W0,
    const float* __restrict__ bias0, u16* __restrict__ C0,
    const u16* __restrict__ A1, const u16* __restrict__ W1,
    const float* __restrict__ bias1, u16* __restrict__ C1,
    int M, int N, int K)
{
    const u16*   A    = blockIdx.z ? A1 : A0;
    const u16*   W    = blockIdx.z ? W1 : W0;
    const float* bias = blockIdx.z ? bias1 : bias0;
    u16*         C    = blockIdx.z ? C1 : C0;

    // 16.4 KB staging during K-loop; reused as 17.4 KB epilogue scratch
    __shared__ __align__(16) char smem[4 * 16 * 68 * 4];
    u16* sA = (u16*)smem;            // [128][32]
    u16* sB = sA + 128 * 32;         // [128][32]

    const int tid  = threadIdx.x;
    const int lane = tid & 63;
    const int wave = tid >> 6;
    const int wm   = wave & 1;
    const int wn   = wave >> 1;
    const int m0   = blockIdx.y * 128;
    const int n0   = blockIdx.x * 128;

    f32x4 acc[4][4];
#pragma unroll
    for (int i = 0; i < 4; ++i)
#pragma unroll
        for (int j = 0; j < 4; ++j)
            acc[i][j] = (f32x4){0.f, 0.f, 0.f, 0.f};

    const int c0 = wave * 64 + lane;
    const int c1 = c0 + 256;
    const int r0 = c0 >> 2, kc0 = (c0 & 3) * 8;
    const int r1 = c1 >> 2, kc1 = (c1 & 3) * 8;
    const u16* gA0 = A + (size_t)(m0 + r0) * K + kc0;
    const u16* gA1 = A + (size_t)(m0 + r1) * K + kc1;
    const u16* gW0 = W + (size_t)(n0 + r0) * K + kc0;
    const u16* gW1 = W + (size_t)(n0 + r1) * K + kc1;
    u16* lA0 = sA + (size_t)(wave * 64) * 8;
    u16* lA1 = sA + (size_t)(256 + wave * 64) * 8;
    u16* lB0 = sB + (size_t)(wave * 64) * 8;
    u16* lB1 = sB + (size_t)(256 + wave * 64) * 8;

    const int aoff = (wm * 64 + (lane & 15)) * 32 + (lane >> 4) * 8;
    const int boff = (wn * 64 + (lane & 15)) * 32 + (lane >> 4) * 8;

    for (int k0 = 0; k0 < K; k0 += 32) {
        __syncthreads();
        gload_lds16(gA0 + k0, lA0);
        gload_lds16(gA1 + k0, lA1);
        gload_lds16(gW0 + k0, lB0);
        gload_lds16(gW1 + k0, lB1);
        __syncthreads();

        short8 af[4], bfr[4];
#pragma unroll
        for (int t = 0; t < 4; ++t) {
            af[t]  = *(const short8*)(sA + aoff + t * 16 * 32);
            bfr[t] = *(const short8*)(sB + boff + t * 16 * 32);
        }
#pragma unroll
        for (int tm = 0; tm < 4; ++tm)
#pragma unroll
            for (int tn = 0; tn < 4; ++tn)
                acc[tm][tn] = __builtin_amdgcn_mfma_f32_16x16x32_bf16(
                    af[tm], bfr[tn], acc[tm][tn], 0, 0, 0);
    }

    // ---- epilogue: wave-private LDS transpose -> coalesced 16B bf16 stores
    float bv[4];
    const int l15 = lane & 15;
#pragma unroll
    for (int tn = 0; tn < 4; ++tn)
        bv[tn] = bias[n0 + wn * 64 + tn * 16 + l15];

    __syncthreads();   // all waves done with sA/sB fragment reads
    float* sE = (float*)smem + wave * (16 * 68);   // 16 rows x 68 (pad) floats
    const int lq4  = (lane >> 4) * 4;
    const int erow = lane >> 3;          // 0..7
    const int ecol = (lane & 7) * 8;     // 0..56

#pragma unroll
    for (int tm = 0; tm < 4; ++tm) {
        // scatter C/D-layout values (col=l15+16tn, row=lq4+r) into [row][col]
#pragma unroll
        for (int tn = 0; tn < 4; ++tn)
#pragma unroll
            for (int r = 0; r < 4; ++r)
                sE[(lq4 + r) * 68 + tn * 16 + l15] = acc[tm][tn][r] + bv[tn];
        // DS ops are in-order per wave: read-after-write / next-tm WAR safe
#pragma unroll
        for (int p = 0; p < 2; ++p) {
            const int rr = p * 8 + erow;
            float4 v0 = *(const float4*)(sE + rr * 68 + ecol);
            float4 v1 = *(const float4*)(sE + rr * 68 + ecol + 4);
            const int grow = m0 + wm * 64 + tm * 16 + rr;
            const int gcol = n0 + wn * 64 + ecol;
            *(ushort8v*)(C + (size_t)grow * N + gcol) = cvt8(v0, v1);
        }
    }
}

// ---------------------------------------------------------------------------
// Pointwise: wave-per-row, no LDS, no barriers, two-pass gates.
// ---------------------------------------------------------------------------
__global__ __launch_bounds__(256) void lstm_pointwise(
    const u16* __restrict__ i2h, const u16* __restrict__ h2h,
    const float* __restrict__ cx,
    const float* __restrict__ lwx, const float* __restrict__ lbx,
    const float* __restrict__ lwy, const float* __restrict__ lby,
    const float* __restrict__ lwc, const float* __restrict__ lbc,
    float* __restrict__ hx_out, float* __restrict__ cx_out)
{
    const int lane = threadIdx.x & 63;
    const int row  = blockIdx.x * 4 + (threadIdx.x >> 6);

    const u16* xr = i2h + (size_t)row * H4;
    const u16* yr = h2h + (size_t)row * H4;

    // ---- pass 1: sums over both 4096-wide rows
    float sx = 0.f, sxx = 0.f, sy = 0.f, syy = 0.f;
#pragma unroll
    for (int g = 0; g < 4; ++g)
#pragma unroll
        for (int h = 0; h < 2; ++h) {
            const int off = g * NH + h * 512 + lane * 8;
            ushort8v xv = *(const ushort8v*)(xr + off);
            ushort8v yv = *(const ushort8v*)(yr + off);
#pragma unroll
            for (int e = 0; e < 8; ++e) {
                float x = bf2f(xv[e]), y = bf2f(yv[e]);
                sx += x; sxx += x * x; sy += y; syy += y * y;
            }
        }
#pragma unroll
    for (int m = 32; m; m >>= 1) {
        sx  += __shfl_xor(sx,  m, 64);
        sxx += __shfl_xor(sxx, m, 64);
        sy  += __shfl_xor(sy,  m, 64);
        syy += __shfl_xor(syy, m, 64);
    }
    const float n1  = (float)H4;
    const float mx  = sx / n1;
    const float ivx = 1.0f / (sqrtf(fmaxf((sxx - sx * sx / n1) / (n1 - 1.f), 0.f)) + LN_EPS);
    const float my  = sy / n1;
    const float ivy = 1.0f / (sqrtf(fmaxf((syy - sy * sy / n1) / (n1 - 1.f), 0.f)) + LN_EPS);

    // ---- pass 2: gates (re-read, L2-hot), cx_new
    float og[16], cvv[16];
    float sc = 0.f, scc = 0.f;
    const float* cxr = cx     + (size_t)row * NH;
    float*       cor = cx_out + (size_t)row * NH;
#pragma unroll
    for (int h = 0; h < 2; ++h) {
        const int j = h * 512 + lane * 8;
        ushort8v gx[4], gy[4];
#pragma unroll
        for (int g = 0; g < 4; ++g) {
            gx[g] = *(const ushort8v*)(xr + g * NH + j);
            gy[g] = *(const ushort8v*)(yr + g * NH + j);
        }
        float cin[8];
        ld8(cxr + j, cin);
        float gate[4][8];
#pragma unroll
        for (int g = 0; g < 4; ++g) {
            float wxa[8], bxa[8], wya[8], bya[8];
            ld8(lwx + g * NH + j, wxa);
            ld8(lbx + g * NH + j, bxa);
            ld8(lwy + g * NH + j, wya);
            ld8(lby + g * NH + j, bya);
#pragma unroll
            for (int e = 0; e < 8; ++e)
                gate[g][e] = (bf2f(gx[g][e]) - mx) * ivx * wxa[e] + bxa[e]
                           + (bf2f(gy[g][e]) - my) * ivy * wya[e] + bya[e];
        }
        float cl[8];
#pragma unroll
        for (int e = 0; e < 8; ++e) {
            float ing = fast_sigmoid(gate[0][e]);
            float fg  = fast_sigmoid(gate[1][e] + FGB);
            og[h * 8 + e] = fast_sigmoid(gate[2][e]);
            float tr  = fast_tanh(gate[3][e]);
            float cc  = fg * cin[e] + ing * tr;
            cvv[h * 8 + e] = cc; cl[e] = cc;
            sc += cc; scc += cc * cc;
        }
        st8(cor + j, cl);
    }
#pragma unroll
    for (int m = 32; m; m >>= 1) {
        sc  += __shfl_xor(sc,  m, 64);
        scc += __shfl_xor(scc, m, 64);
    }
    const float nc  = (float)NH;
    const float mc  = sc / nc;
    const float ivc = 1.0f / (sqrtf(fmaxf((scc - sc * sc / nc) / (nc - 1.f), 0.f)) + LN_EPS);

    // ---- pass 3: hx_new
    float* hor = hx_out + (size_t)row * NH;
#pragma unroll
    for (int h = 0; h < 2; ++h) {
        const int j = h * 512 + lane * 8;
        float wca[8], bca[8], o[8];
        ld8(lwc + j, wca);
        ld8(lbc + j, bca);
#pragma unroll
        for (int e = 0; e < 8; ++e)
            o[e] = og[h * 8 + e] * fast_tanh((cvv[h * 8 + e] - mc) * ivc * wca[e] + bca[e]);
        st8(hor + j, o);
    }
}

// ---------------------------------------------------------------------------
extern "C" void kernel_launch(void* const* d_in, const int* in_sizes, int n_in,
                              void* d_out, int out_size, void* d_ws, size_t ws_size,
                              hipStream_t stream) {
    const float* inputs = (const float*)d_in[0];
    const float* hx     = (const float*)d_in[1];
    const float* cx     = (const float*)d_in[2];
    const float* w_i2h  = (const float*)d_in[3];
    const float* b_i2h  = (const float*)d_in[4];
    const float* w_h2h  = (const float*)d_in[5];
    const float* b_h2h  = (const float*)d_in[6];
    const float* lwx    = (const float*)d_in[7];
    const float* lbx    = (const float*)d_in[8];
    const float* lwy    = (const float*)d_in[9];
    const float* lby    = (const float*)d_in[10];
    const float* lwc    = (const float*)d_in[11];
    const float* lbc    = (const float*)d_in[12];

    const int B = in_sizes[0] / NI;                // 4096

    u16* a_bf   = (u16*)d_ws;
    u16* hx_bf  = a_bf   + (size_t)B * NI;
    u16* wi_bf  = hx_bf  + (size_t)B * NH;
    u16* wh_bf  = wi_bf  + (size_t)H4 * NI;
    u16* i2h_bf = wh_bf  + (size_t)H4 * NH;
    u16* h2h_bf = i2h_bf + (size_t)B * H4;

    float* hx_out = (float*)d_out;
    float* cx_out = hx_out + (size_t)B * NH;

    cast4<<<dim3((B * NI) / (256 * 8)), dim3(256), 0, stream>>>(
        inputs, hx, w_i2h, w_h2h, a_bf, hx_bf, wi_bf, wh_bf);

    gemm_bt_bf16<<<dim3(H4 / 128, B / 128, 2), dim3(256), 0, stream>>>(
        a_bf, wi_bf, b_i2h, i2h_bf,
        hx_bf, wh_bf, b_h2h, h2h_bf,
        B, H4, NI);

    lstm_pointwise<<<dim3(B / 4), dim3(256), 0, stream>>>(
        i2h_bf, h2h_bf, cx, lwx, lbx, lwy, lby, lwc, lbc, hx_out, cx_out);
}

// Round 4
// 266.622 us; speedup vs baseline: 1.0140x; 1.0140x over previous
//
#include <hip/hip_runtime.h>
#include <hip/hip_bf16.h>
#include <math.h>

#define NI 1024        // NUM_INPUTS
#define NH 1024        // NUM_HIDDEN
#define H4 4096        // 4*NUM_HIDDEN
#define FGB (-1.0f)
#define LN_EPS 1e-5f

typedef unsigned short u16;
typedef __attribute__((ext_vector_type(8))) short short8;      // 8 bf16 (MFMA frag)
typedef __attribute__((ext_vector_type(8))) unsigned short ushort8v;
typedef __attribute__((ext_vector_type(16))) float f32x16;     // 32x32 accumulator

__device__ __forceinline__ float bf2f(u16 u) {
    union { unsigned int i; float f; } v; v.i = ((unsigned int)u) << 16; return v.f;
}
__device__ __forceinline__ u16 f2bf(float f) {
    __hip_bfloat16 h = __float2bfloat16(f);   // RNE
    return __builtin_bit_cast(u16, h);
}
__device__ __forceinline__ ushort8v cvt8(float4 lo, float4 hi) {
    ushort8v r;
    r[0] = f2bf(lo.x); r[1] = f2bf(lo.y); r[2] = f2bf(lo.z); r[3] = f2bf(lo.w);
    r[4] = f2bf(hi.x); r[5] = f2bf(hi.y); r[6] = f2bf(hi.z); r[7] = f2bf(hi.w);
    return r;
}
__device__ __forceinline__ float fast_sigmoid(float x) {
    return 1.0f / (1.0f + __expf(-x));
}
__device__ __forceinline__ float fast_tanh(float x) {
    return 1.0f - 2.0f / (__expf(2.0f * x) + 1.0f);
}
__device__ __forceinline__ void gload_lds16(const u16* g, u16* l) {
    __builtin_amdgcn_global_load_lds(
        (__attribute__((address_space(1))) void*)(g),
        (__attribute__((address_space(3))) void*)(l), 16, 0, 0);
}

// ---------------------------------------------------------------------------
// fp32 -> bf16 cast, 8 elems/thread, 16B stores
// ---------------------------------------------------------------------------
__global__ __launch_bounds__(256) void cast4(
    const float* __restrict__ a, const float* __restrict__ b,
    const float* __restrict__ c, const float* __restrict__ d,
    u16* __restrict__ oa, u16* __restrict__ ob,
    u16* __restrict__ oc, u16* __restrict__ od)
{
    const int i = (blockIdx.x * 256 + threadIdx.x) * 8;
    *(ushort8v*)(oa + i) = cvt8(*(const float4*)(a + i), *(const float4*)(a + i + 4));
    *(ushort8v*)(ob + i) = cvt8(*(const float4*)(b + i), *(const float4*)(b + i + 4));
    *(ushort8v*)(oc + i) = cvt8(*(const float4*)(c + i), *(const float4*)(c + i + 4));
    *(ushort8v*)(od + i) = cvt8(*(const float4*)(d + i), *(const float4*)(d + i + 4));
}

// ---------------------------------------------------------------------------
// C[M,N](bf16) = A[M,K](bf16) @ W[N,K](bf16)^T + bias[N](fp32)
// 128x128 tile, BK=32, 4 waves, each wave = 2x2 tiles of 32x32x16 MFMA.
// global_load_lds width=16 staging (m97-verified). blockIdx.z picks GEMM 0/1.
// ---------------------------------------------------------------------------
__global__ __launch_bounds__(256) void gemm_bt_bf16(
    const u16* __restrict__ A0, const u16* __restrict__ W0,
    const float* __restrict__ bias0, u16* __restrict__ C0,
    const u16* __restrict__ A1, const u16* __restrict__ W1,
    const float* __restrict__ bias1, u16* __restrict__ C1,
    int M, int N, int K)
{
    const u16*   A    = blockIdx.z ? A1 : A0;
    const u16*   W    = blockIdx.z ? W1 : W0;
    const float* bias = blockIdx.z ? bias1 : bias0;
    u16*         C    = blockIdx.z ? C1 : C0;

    __shared__ u16 sA[128 * 32];   // [m][k], 8 KB
    __shared__ u16 sB[128 * 32];   // [n][k], 8 KB

    const int tid  = threadIdx.x;
    const int lane = tid & 63;
    const int wave = tid >> 6;
    const int wm   = wave & 1;
    const int wn   = wave >> 1;
    const int m0   = blockIdx.y * 128;
    const int n0   = blockIdx.x * 128;

    f32x16 acc[2][2];
#pragma unroll
    for (int i = 0; i < 2; ++i)
#pragma unroll
        for (int j = 0; j < 2; ++j)
#pragma unroll
            for (int r = 0; r < 16; ++r)
                acc[i][j][r] = 0.f;

    // staging: 512 chunks of 16B per tile; chunk c -> row c>>2, kcol (c&3)*8
    const int c0 = wave * 64 + lane;
    const int c1 = c0 + 256;
    const int r0 = c0 >> 2, kc0 = (c0 & 3) * 8;
    const int r1 = c1 >> 2, kc1 = (c1 & 3) * 8;
    const u16* gA0 = A + (size_t)(m0 + r0) * K + kc0;
    const u16* gA1 = A + (size_t)(m0 + r1) * K + kc1;
    const u16* gW0 = W + (size_t)(n0 + r0) * K + kc0;
    const u16* gW1 = W + (size_t)(n0 + r1) * K + kc1;
    u16* lA0 = sA + (size_t)(wave * 64) * 8;
    u16* lA1 = sA + (size_t)(256 + wave * 64) * 8;
    u16* lB0 = sB + (size_t)(wave * 64) * 8;
    u16* lB1 = sB + (size_t)(256 + wave * 64) * 8;

    // 32x32x16 A/B fragment: m(or n) = lane&31, k = (lane>>5)*8 + j
    const int l31  = lane & 31;
    const int kgrp = (lane >> 5) * 8;
    const int aoff = (wm * 64 + l31) * 32 + kgrp;
    const int boff = (wn * 64 + l31) * 32 + kgrp;

    for (int k0 = 0; k0 < K; k0 += 32) {
        __syncthreads();
        gload_lds16(gA0 + k0, lA0);
        gload_lds16(gA1 + k0, lA1);
        gload_lds16(gW0 + k0, lB0);
        gload_lds16(gW1 + k0, lB1);
        __syncthreads();

#pragma unroll
        for (int kh = 0; kh < 2; ++kh) {   // two K=16 halves of the BK=32 tile
            short8 a0 = *(const short8*)(sA + aoff + kh * 16);
            short8 a1 = *(const short8*)(sA + aoff + 32 * 32 + kh * 16);
            short8 b0 = *(const short8*)(sB + boff + kh * 16);
            short8 b1 = *(const short8*)(sB + boff + 32 * 32 + kh * 16);
            acc[0][0] = __builtin_amdgcn_mfma_f32_32x32x16_bf16(a0, b0, acc[0][0], 0, 0, 0);
            acc[0][1] = __builtin_amdgcn_mfma_f32_32x32x16_bf16(a0, b1, acc[0][1], 0, 0, 0);
            acc[1][0] = __builtin_amdgcn_mfma_f32_32x32x16_bf16(a1, b0, acc[1][0], 0, 0, 0);
            acc[1][1] = __builtin_amdgcn_mfma_f32_32x32x16_bf16(a1, b1, acc[1][1], 0, 0, 0);
        }
    }

    // epilogue: C/D layout col = lane&31, row = (reg&3) + 8*(reg>>2) + 4*(lane>>5)
    float bv[2];
#pragma unroll
    for (int tn = 0; tn < 2; ++tn)
        bv[tn] = bias[n0 + wn * 64 + tn * 32 + l31];

    const int rbase = (lane >> 5) * 4;
#pragma unroll
    for (int tm = 0; tm < 2; ++tm)
#pragma unroll
        for (int tn = 0; tn < 2; ++tn) {
            const int col = n0 + wn * 64 + tn * 32 + l31;
#pragma unroll
            for (int reg = 0; reg < 16; ++reg) {
                const int row = m0 + wm * 64 + tm * 32 + (reg & 3) + 8 * (reg >> 2) + rbase;
                C[(size_t)row * N + col] = f2bf(acc[tm][tn][reg] + bv[tn]);
            }
        }
}

// ---------------------------------------------------------------------------
// Pointwise: block-per-row, single HBM pass, bf16 LDS staging (16 KB).
// ---------------------------------------------------------------------------
__global__ __launch_bounds__(256) void lstm_pointwise(
    const u16* __restrict__ i2h, const u16* __restrict__ h2h,
    const float* __restrict__ cx,
    const float* __restrict__ lwx, const float* __restrict__ lbx,
    const float* __restrict__ lwy, const float* __restrict__ lby,
    const float* __restrict__ lwc, const float* __restrict__ lbc,
    float* __restrict__ hx_out, float* __restrict__ cx_out)
{
    __shared__ u16 sX[H4];
    __shared__ u16 sY[H4];
    __shared__ float red[16];

    const int row  = blockIdx.x;
    const int tid  = threadIdx.x;
    const int lane = tid & 63;
    const int wid  = tid >> 6;

    const u16* xr = i2h + (size_t)row * H4;
    const u16* yr = h2h + (size_t)row * H4;

    // ---- stage rows into LDS (bf16), accumulate sum/sumsq
    float sx = 0.f, sxx = 0.f, sy = 0.f, syy = 0.f;
#pragma unroll
    for (int s = 0; s < 2; ++s) {
        const int off = s * 2048 + tid * 8;
        ushort8v xv = *(const ushort8v*)(xr + off);
        ushort8v yv = *(const ushort8v*)(yr + off);
        *(ushort8v*)(sX + off) = xv;
        *(ushort8v*)(sY + off) = yv;
#pragma unroll
        for (int e = 0; e < 8; ++e) {
            float x = bf2f(xv[e]), y = bf2f(yv[e]);
            sx += x; sxx += x * x; sy += y; syy += y * y;
        }
    }
#pragma unroll
    for (int m = 32; m; m >>= 1) {
        sx  += __shfl_xor(sx,  m, 64);
        sxx += __shfl_xor(sxx, m, 64);
        sy  += __shfl_xor(sy,  m, 64);
        syy += __shfl_xor(syy, m, 64);
    }
    if (lane == 0) {
        red[wid] = sx; red[4 + wid] = sxx; red[8 + wid] = sy; red[12 + wid] = syy;
    }
    __syncthreads();
    const float tsx  = red[0] + red[1] + red[2] + red[3];
    const float tsxx = red[4] + red[5] + red[6] + red[7];
    const float tsy  = red[8] + red[9] + red[10] + red[11];
    const float tsyy = red[12] + red[13] + red[14] + red[15];
    __syncthreads();   // red reused

    const float n1  = (float)H4;
    const float mx  = tsx / n1;
    const float ivx = 1.0f / (sqrtf(fmaxf((tsxx - tsx * tsx / n1) / (n1 - 1.f), 0.f)) + LN_EPS);
    const float my  = tsy / n1;
    const float ivy = 1.0f / (sqrtf(fmaxf((tsyy - tsy * tsy / n1) / (n1 - 1.f), 0.f)) + LN_EPS);

    // ---- gates from LDS, cx_new
    const int j0 = tid * 4;
    float gate[4][4];
#pragma unroll
    for (int g = 0; g < 4; ++g) {
        ushort4 xv = *(const ushort4*)(sX + g * NH + j0);
        ushort4 yv = *(const ushort4*)(sY + g * NH + j0);
        float4 wxv = *(const float4*)(lwx + g * NH + j0);
        float4 bxv = *(const float4*)(lbx + g * NH + j0);
        float4 wyv = *(const float4*)(lwy + g * NH + j0);
        float4 byv = *(const float4*)(lby + g * NH + j0);
        gate[g][0] = (bf2f(xv.x) - mx) * ivx * wxv.x + bxv.x + (bf2f(yv.x) - my) * ivy * wyv.x + byv.x;
        gate[g][1] = (bf2f(xv.y) - mx) * ivx * wxv.y + bxv.y + (bf2f(yv.y) - my) * ivy * wyv.y + byv.y;
        gate[g][2] = (bf2f(xv.z) - mx) * ivx * wxv.z + bxv.z + (bf2f(yv.z) - my) * ivy * wyv.z + byv.z;
        gate[g][3] = (bf2f(xv.w) - mx) * ivx * wxv.w + bxv.w + (bf2f(yv.w) - my) * ivy * wyv.w + byv.w;
    }

    float4 cxv = *(const float4*)(cx + (size_t)row * NH + j0);
    const float cin[4] = {cxv.x, cxv.y, cxv.z, cxv.w};
    float cvl[4], og[4];
    float sc = 0.f, scc = 0.f;
#pragma unroll
    for (int e = 0; e < 4; ++e) {
        float ing = fast_sigmoid(gate[0][e]);
        float fg  = fast_sigmoid(gate[1][e] + FGB);
        og[e]     = fast_sigmoid(gate[2][e]);
        float tr  = fast_tanh(gate[3][e]);
        float c   = fg * cin[e] + ing * tr;
        cvl[e] = c; sc += c; scc += c * c;
    }
    *(float4*)(cx_out + (size_t)row * NH + j0) = make_float4(cvl[0], cvl[1], cvl[2], cvl[3]);

#pragma unroll
    for (int m = 32; m; m >>= 1) {
        sc  += __shfl_xor(sc,  m, 64);
        scc += __shfl_xor(scc, m, 64);
    }
    if (lane == 0) { red[wid] = sc; red[4 + wid] = scc; }
    __syncthreads();
    const float tsc  = red[0] + red[1] + red[2] + red[3];
    const float tscc = red[4] + red[5] + red[6] + red[7];

    const float nc  = (float)NH;
    const float mc  = tsc / nc;
    const float ivc = 1.0f / (sqrtf(fmaxf((tscc - tsc * tsc / nc) / (nc - 1.f), 0.f)) + LN_EPS);

    float4 wcv = *(const float4*)(lwc + j0);
    float4 bcv = *(const float4*)(lbc + j0);
    float h0 = og[0] * fast_tanh((cvl[0] - mc) * ivc * wcv.x + bcv.x);
    float h1 = og[1] * fast_tanh((cvl[1] - mc) * ivc * wcv.y + bcv.y);
    float h2 = og[2] * fast_tanh((cvl[2] - mc) * ivc * wcv.z + bcv.z);
    float h3 = og[3] * fast_tanh((cvl[3] - mc) * ivc * wcv.w + bcv.w);
    *(float4*)(hx_out + (size_t)row * NH + j0) = make_float4(h0, h1, h2, h3);
}

// ---------------------------------------------------------------------------
extern "C" void kernel_launch(void* const* d_in, const int* in_sizes, int n_in,
                              void* d_out, int out_size, void* d_ws, size_t ws_size,
                              hipStream_t stream) {
    const float* inputs = (const float*)d_in[0];
    const float* hx     = (const float*)d_in[1];
    const float* cx     = (const float*)d_in[2];
    const float* w_i2h  = (const float*)d_in[3];
    const float* b_i2h  = (const float*)d_in[4];
    const float* w_h2h  = (const float*)d_in[5];
    const float* b_h2h  = (const float*)d_in[6];
    const float* lwx    = (const float*)d_in[7];
    const float* lbx    = (const float*)d_in[8];
    const float* lwy    = (const float*)d_in[9];
    const float* lby    = (const float*)d_in[10];
    const float* lwc    = (const float*)d_in[11];
    const float* lbc    = (const float*)d_in[12];

    const int B = in_sizes[0] / NI;                // 4096

    u16* a_bf   = (u16*)d_ws;
    u16* hx_bf  = a_bf   + (size_t)B * NI;
    u16* wi_bf  = hx_bf  + (size_t)B * NH;
    u16* wh_bf  = wi_bf  + (size_t)H4 * NI;
    u16* i2h_bf = wh_bf  + (size_t)H4 * NH;
    u16* h2h_bf = i2h_bf + (size_t)B * H4;

    float* hx_out = (float*)d_out;
    float* cx_out = hx_out + (size_t)B * NH;

    cast4<<<dim3((B * NI) / (256 * 8)), dim3(256), 0, stream>>>(
        inputs, hx, w_i2h, w_h2h, a_bf, hx_bf, wi_bf, wh_bf);

    gemm_bt_bf16<<<dim3(H4 / 128, B / 128, 2), dim3(256), 0, stream>>>(
        a_bf, wi_bf, b_i2h, i2h_bf,
        hx_bf, wh_bf, b_h2h, h2h_bf,
        B, H4, NI);

    lstm_pointwise<<<dim3(B), dim3(256), 0, stream>>>(
        i2h_bf, h2h_bf, cx, lwx, lbx, lwy, lby, lwc, lbc, hx_out, cx_out);
}